// Round 1
// baseline (130.817 us; speedup 1.0000x reference)
//
#include <hip/hip_runtime.h>

// SpatialAttention B=4 HW=4096 C=256 NH=4 d=64 — f16 MFMA flash attention.
// R6 (= R5 + occupancy): grid is hard-capped at 2 blocks/CU (512 wgs / 256 CUs),
// so 4-wave blocks gave only ~6 waves/CU — softmax VALU could not overlap MFMA
// across waves (VALUBusy 51 + MfmaUtil 36, both starved). Now 8-wave (512-thr)
// blocks, each wave owns 16 q-rows (g-dim stripped): 16 waves/CU = 4/SIMD,
// same LDS tiles, same K/V L2 traffic, fewer VGPRs. Staging is 2 gload_lds
// per thread (8 waves x 1KB per 8KB tile).

#define HW 4096
#define CCH 256
#define DH 64
#define NH 4
#define QTILE 128
#define KTILE 64
#define NKT (HW / KTILE)
#define LOG2E 1.44269504088896340736f

typedef __attribute__((ext_vector_type(8))) _Float16 half8;
typedef __attribute__((ext_vector_type(4))) _Float16 half4;
typedef __attribute__((ext_vector_type(2))) __fp16 pk16x2;   // cvt_pkrtz native type
typedef __attribute__((ext_vector_type(4))) float floatx4;

typedef __attribute__((address_space(1))) const unsigned int gbl_u32;
typedef __attribute__((address_space(3))) unsigned int lds_u32;

__device__ __forceinline__ void gload_lds16(const void* g, void* l) {
    __builtin_amdgcn_global_load_lds((gbl_u32*)g, (lds_u32*)l, 16, 0, 0);
}
__device__ __forceinline__ floatx4 mfma_k32(half8 a, half8 b, floatx4 c) {
    return __builtin_amdgcn_mfma_f32_16x16x32_f16(a, b, c, 0, 0, 0);
}
__device__ __forceinline__ floatx4 mfma_k16(half4 a, half4 b, floatx4 c) {
    return __builtin_amdgcn_mfma_f32_16x16x16f16(a, b, c, 0, 0, 0);
}

// ---------- fused prepass ----------
// blocks [0,4096): Qhat/Khat elementwise (scale*log2e folded into Q)
// blocks [4096,5120): Vthat transpose [B*NH][64][HW]
__global__ __launch_bounds__(256) void prepass_all(
    const float* __restrict__ q_in, const float* __restrict__ k_in,
    const float* __restrict__ v_in,
    const float* __restrict__ wq, const float* __restrict__ bq,
    const float* __restrict__ wk, const float* __restrict__ bk,
    const float* __restrict__ wv, const float* __restrict__ bv,
    _Float16* __restrict__ Qhat, _Float16* __restrict__ Khat,
    _Float16* __restrict__ Vthat)
{
    if (blockIdx.x < 4096) {
        int idx = (blockIdx.x * 256 + threadIdx.x) * 4;
        int b = idx >> 20;
        int rem = idx & ((1 << 20) - 1);
        int row = rem >> 8;
        int c = rem & 255;
        int h = c >> 6;
        int ch = c & 63;
        floatx4 q4 = *(const floatx4*)(q_in + idx);
        floatx4 k4 = *(const floatx4*)(k_in + idx);
        floatx4 wq4 = *(const floatx4*)(wq + c);
        floatx4 bq4 = *(const floatx4*)(bq + c);
        floatx4 wk4 = *(const floatx4*)(wk + c);
        floatx4 bk4 = *(const floatx4*)(bk + c);
        const float qsc = 0.125f * LOG2E;
        half4 qh, kh;
        qh[0] = (_Float16)((q4.x * wq4.x + bq4.x) * qsc);
        qh[1] = (_Float16)((q4.y * wq4.y + bq4.y) * qsc);
        qh[2] = (_Float16)((q4.z * wq4.z + bq4.z) * qsc);
        qh[3] = (_Float16)((q4.w * wq4.w + bq4.w) * qsc);
        kh[0] = (_Float16)(k4.x * wk4.x + bk4.x);
        kh[1] = (_Float16)(k4.y * wk4.y + bk4.y);
        kh[2] = (_Float16)(k4.z * wk4.z + bk4.z);
        kh[3] = (_Float16)(k4.w * wk4.w + bk4.w);
        size_t o = ((size_t)(b * NH + h) * HW + row) * DH + ch;
        *(half4*)(Qhat + o) = qh;
        *(half4*)(Khat + o) = kh;
    } else {
        __shared__ _Float16 Lt[64 * 68];
        int bx = blockIdx.x - 4096;
        int t = threadIdx.x;
        int key0 = (bx & 63) * 64;
        int bh = bx >> 6;
        int b = bh >> 2, h = bh & 3;
        int c4 = (t & 15) * 4;
        floatx4 wv4 = *(const floatx4*)(wv + h * DH + c4);
        floatx4 bv4 = *(const floatx4*)(bv + h * DH + c4);
        #pragma unroll
        for (int p = 0; p < 4; ++p) {
            int key = p * 16 + (t >> 4);
            const float* vp = v_in + ((size_t)b * HW + key0 + key) * CCH + h * DH + c4;
            floatx4 v4 = *(const floatx4*)vp;
            half4 vh;
            vh[0] = (_Float16)(v4.x * wv4.x + bv4.x);
            vh[1] = (_Float16)(v4.y * wv4.y + bv4.y);
            vh[2] = (_Float16)(v4.z * wv4.z + bv4.z);
            vh[3] = (_Float16)(v4.w * wv4.w + bv4.w);
            *(half4*)(&Lt[key * 68 + c4]) = vh;
        }
        __syncthreads();
        #pragma unroll
        for (int p = 0; p < 2; ++p) {
            int ch = p * 32 + (t >> 3);
            int kg = (t & 7) * 8;
            half8 v8;
            #pragma unroll
            for (int j = 0; j < 8; ++j) v8[j] = Lt[(kg + j) * 68 + ch];
            *(half8*)(Vthat + ((size_t)bh * DH + ch) * HW + key0 + kg) = v8;
        }
    }
}

// ---------- attention (transposed, register-P, 8-wave blocks) ----------
__launch_bounds__(512, 4)
__global__ void attn_kernel(
    const _Float16* __restrict__ Qhat, const _Float16* __restrict__ Khat,
    const _Float16* __restrict__ Vthat,
    const float* __restrict__ wp, const float* __restrict__ bp,
    float* __restrict__ out)
{
    // pool: Ksm0 | Ksm1 | Vsm0 | Vsm1 (8KB each); epilogue reuses as Ot
    __shared__ alignas(16) char pool[36864];
    _Float16* Ksm0 = (_Float16*)(pool);
    _Float16* Ksm1 = (_Float16*)(pool + 8192);
    _Float16* Vsm0 = (_Float16*)(pool + 16384);
    _Float16* Vsm1 = (_Float16*)(pool + 24576);

    const int tid = threadIdx.x;
    const int wave = tid >> 6;      // 0..7
    const int lane = tid & 63;
    const int l15 = lane & 15;
    const int quad = lane >> 4;
    const int ksw = l15 & 7;

    const int qtile = blockIdx.x;
    const int bh = blockIdx.y;

    // Q B-frags: B[k=ch][n=q], lane holds ch = quad*8+j (+32), q = l15
    const int q0 = qtile * QTILE + wave * 16;
    half8 qfrag[2];
    {
        const _Float16* qp = Qhat + ((size_t)bh * HW + q0 + l15) * DH + quad * 8;
        qfrag[0] = *(const half8*)(qp);
        qfrag[1] = *(const half8*)(qp + 32);
    }

    // staging lane addresses (XOR swizzle of 8-half groups in global addr)
    // 8 waves x 8 rows = full 64-row tile, 1KB per wave per tensor
    const int srow0 = lane >> 3;
    const int sw = (lane & 7) ^ srow0;
    const _Float16* kgp = Khat + ((size_t)bh * HW + wave * 8 + srow0) * DH + sw * 8;
    const _Float16* vgp = Vthat + ((size_t)bh * DH + wave * 8 + srow0) * HW + sw * 8;

    floatx4 acc[4];
    float m_i = -1e30f, l_i = 0.0f;
    #pragma unroll
    for (int nt = 0; nt < 4; ++nt) { floatx4 z = {0.f,0.f,0.f,0.f}; acc[nt] = z; }

    #define STAGE(kt, KB, VB) do {                                             \
        gload_lds16(kgp + (size_t)(kt) * (KTILE * DH), (KB) + wave * 512);     \
        gload_lds16(vgp + (size_t)(kt) * KTILE, (VB) + wave * 512);            \
    } while (0)

    #define COMPUTE(KB, VB) do {                                               \
        floatx4 S[4];                                                          \
        _Pragma("unroll")                                                      \
        for (int kt = 0; kt < 4; ++kt) {                                       \
            const _Float16* kr = (KB) + (l15 + 16 * kt) * 64;                  \
            half8 kf0 = *(const half8*)(kr + ((quad ^ ksw) * 8));              \
            half8 kf1 = *(const half8*)(kr + (((4 + quad) ^ ksw) * 8));        \
            floatx4 s = {0.f, 0.f, 0.f, 0.f};                                  \
            s = mfma_k32(kf0, qfrag[0], s);                                    \
            s = mfma_k32(kf1, qfrag[1], s);                                    \
            S[kt] = s;                                                         \
        }                                                                      \
        half4 pfrag[4];                                                        \
        {                                                                      \
            float mx = fmaxf(fmaxf(fmaxf(S[0][0], S[0][1]),                    \
                                   fmaxf(S[0][2], S[0][3])),                   \
                             fmaxf(fmaxf(S[1][0], S[1][1]),                    \
                                   fmaxf(S[1][2], S[1][3])));                  \
            float mx2 = fmaxf(fmaxf(fmaxf(S[2][0], S[2][1]),                   \
                                    fmaxf(S[2][2], S[2][3])),                  \
                              fmaxf(fmaxf(S[3][0], S[3][1]),                   \
                                    fmaxf(S[3][2], S[3][3])));                 \
            mx = fmaxf(mx, mx2);                                               \
            mx = fmaxf(mx, __shfl_xor(mx, 16));                                \
            mx = fmaxf(mx, __shfl_xor(mx, 32));                                \
            float nm = fmaxf(m_i, mx);                                         \
            float alpha = __builtin_amdgcn_exp2f(m_i - nm);                    \
            float rs = 0.0f;                                                   \
            _Pragma("unroll")                                                  \
            for (int kt = 0; kt < 4; ++kt) {                                   \
                float p0 = __builtin_amdgcn_exp2f(S[kt][0] - nm);              \
                float p1 = __builtin_amdgcn_exp2f(S[kt][1] - nm);              \
                float p2 = __builtin_amdgcn_exp2f(S[kt][2] - nm);              \
                float p3 = __builtin_amdgcn_exp2f(S[kt][3] - nm);              \
                rs += (p0 + p1) + (p2 + p3);                                   \
                pk16x2 lo = __builtin_amdgcn_cvt_pkrtz(p0, p1);                \
                pk16x2 hi = __builtin_amdgcn_cvt_pkrtz(p2, p3);                \
                half4 pk;                                                      \
                pk[0] = (_Float16)lo[0]; pk[1] = (_Float16)lo[1];              \
                pk[2] = (_Float16)hi[0]; pk[3] = (_Float16)hi[1];              \
                pfrag[kt] = pk;                                                \
            }                                                                  \
            rs += __shfl_xor(rs, 16);                                          \
            rs += __shfl_xor(rs, 32);                                          \
            l_i = l_i * alpha + rs;                                            \
            m_i = nm;                                                          \
            _Pragma("unroll")                                                  \
            for (int nt = 0; nt < 4; ++nt) acc[nt] *= alpha;                   \
        }                                                                      \
        _Pragma("unroll")                                                      \
        for (int kt = 0; kt < 4; ++kt) {                                       \
            _Pragma("unroll")                                                  \
            for (int nt = 0; nt < 4; ++nt) {                                   \
                const _Float16* vr = (VB) + (l15 + 16 * nt) * 64               \
                    + (((2 * kt + (quad >> 1)) ^ ksw) * 8) + (quad & 1) * 4;   \
                half4 vf = *(const half4*)vr;                                  \
                acc[nt] = mfma_k16(vf, pfrag[kt], acc[nt]);                    \
            }                                                                  \
        }                                                                      \
    } while (0)

    STAGE(0, Ksm0, Vsm0);
    for (int kt = 0; kt < NKT; kt += 2) {
        __syncthreads();
        if (kt + 1 < NKT) STAGE(kt + 1, Ksm1, Vsm1);
        COMPUTE(Ksm0, Vsm0);
        __syncthreads();
        if (kt + 2 < NKT) STAGE(kt + 2, Ksm0, Vsm0);
        COMPUTE(Ksm1, Vsm1);
    }

    // ---- epilogue: transpose O^T through LDS, coalesced stores ----
    const int b = bh >> 2, h = bh & 3, ch0 = h * DH;
    floatx4 wp4 = *(const floatx4*)(wp + ch0 + l15 * 4);
    floatx4 bp4 = *(const floatx4*)(bp + ch0 + l15 * 4);
    float inv_l = 1.0f / l_i;

    __syncthreads();
    float* Ot = (float*)(pool) + wave * 1152;   // [16 q][72] floats, 4608B/wave
    #pragma unroll
    for (int nt = 0; nt < 4; ++nt) {
        floatx4 o;
        #pragma unroll
        for (int r = 0; r < 4; ++r) o[r] = acc[nt][r] * inv_l;
        *(floatx4*)&Ot[l15 * 72 + nt * 16 + quad * 4] = o;
    }
    #pragma unroll
    for (int i = 0; i < 4; ++i) {
        int q = i * 4 + quad;
        floatx4 v = *(const floatx4*)&Ot[q * 72 + l15 * 4];
        floatx4 o;
        o.x = v.x * wp4.x + bp4.x;
        o.y = v.y * wp4.y + bp4.y;
        o.z = v.z * wp4.z + bp4.z;
        o.w = v.w * wp4.w + bp4.w;
        *(floatx4*)(out + ((size_t)b * HW + q0 + q) * CCH + ch0 + l15 * 4) = o;
    }
    #undef STAGE
    #undef COMPUTE
}

extern "C" void kernel_launch(void* const* d_in, const int* in_sizes, int n_in,
                              void* d_out, int out_size, void* d_ws, size_t ws_size,
                              hipStream_t stream) {
    const float* q_in = (const float*)d_in[0];
    const float* k_in = (const float*)d_in[1];
    const float* v_in = (const float*)d_in[2];
    const float* wq = (const float*)d_in[3];
    const float* bq = (const float*)d_in[4];
    const float* wk = (const float*)d_in[5];
    const float* bk = (const float*)d_in[6];
    const float* wv = (const float*)d_in[7];
    const float* bv = (const float*)d_in[8];
    const float* wp = (const float*)d_in[9];
    const float* bp = (const float*)d_in[10];
    float* out = (float*)d_out;

    const size_t tensor_halves = (size_t)4 * NH * HW * DH;
    _Float16* Qhat = (_Float16*)d_ws;
    _Float16* Khat = Qhat + tensor_halves;
    _Float16* Vthat = Khat + tensor_halves;

    prepass_all<<<dim3(4096 + 1024), 256, 0, stream>>>(
        q_in, k_in, v_in, wq, bq, wk, bk, wv, bv, Qhat, Khat, Vthat);
    attn_kernel<<<dim3(HW / QTILE, 4 * NH), 512, 0, stream>>>(
        Qhat, Khat, Vthat, wp, bp, out);
}

// Round 2
// 129.387 us; speedup vs baseline: 1.0111x; 1.0111x over previous
//
#include <hip/hip_runtime.h>

// SpatialAttention B=4 HW=4096 C=256 NH=4 d=64 — f16 MFMA flash attention.
// R7 (= R5 + K-split concurrency): R6 showed occupancy alone regresses when
// q-rows/wave drops (LDS traffic doubled, pipe saturated). Keep 32 q-rows/wave
// (best LDS reuse) and double waves via K-parity split: waves w and w+4 share
// q-rows, process even/odd K-tiles with independent online softmax, merged once
// in epilogue through LDS. 8-wave blocks, QTILE=128, 64KB LDS (2 sets x
// (Kpair 16KB + Vpair 16KB)), 2 blocks/CU -> 16 waves/CU = 4/SIMD.

#define HW 4096
#define CCH 256
#define DH 64
#define NH 4
#define QTILE 128
#define KTILE 64
#define NST 32                    // super-tiles of 2 K-tiles (even+odd)
#define LOG2E 1.44269504088896340736f

typedef __attribute__((ext_vector_type(8))) _Float16 half8;
typedef __attribute__((ext_vector_type(4))) _Float16 half4;
typedef __attribute__((ext_vector_type(2))) __fp16 pk16x2;   // cvt_pkrtz native type
typedef __attribute__((ext_vector_type(4))) float floatx4;

typedef __attribute__((address_space(1))) const unsigned int gbl_u32;
typedef __attribute__((address_space(3))) unsigned int lds_u32;

__device__ __forceinline__ void gload_lds16(const void* g, void* l) {
    __builtin_amdgcn_global_load_lds((gbl_u32*)g, (lds_u32*)l, 16, 0, 0);
}
__device__ __forceinline__ floatx4 mfma_k32(half8 a, half8 b, floatx4 c) {
    return __builtin_amdgcn_mfma_f32_16x16x32_f16(a, b, c, 0, 0, 0);
}
__device__ __forceinline__ floatx4 mfma_k16(half4 a, half4 b, floatx4 c) {
    return __builtin_amdgcn_mfma_f32_16x16x16f16(a, b, c, 0, 0, 0);
}

// ---------- fused prepass ----------
// blocks [0,4096): Qhat/Khat elementwise (scale*log2e folded into Q)
// blocks [4096,5120): Vthat transpose [B*NH][64][HW]
__global__ __launch_bounds__(256) void prepass_all(
    const float* __restrict__ q_in, const float* __restrict__ k_in,
    const float* __restrict__ v_in,
    const float* __restrict__ wq, const float* __restrict__ bq,
    const float* __restrict__ wk, const float* __restrict__ bk,
    const float* __restrict__ wv, const float* __restrict__ bv,
    _Float16* __restrict__ Qhat, _Float16* __restrict__ Khat,
    _Float16* __restrict__ Vthat)
{
    if (blockIdx.x < 4096) {
        int idx = (blockIdx.x * 256 + threadIdx.x) * 4;
        int b = idx >> 20;
        int rem = idx & ((1 << 20) - 1);
        int row = rem >> 8;
        int c = rem & 255;
        int h = c >> 6;
        int ch = c & 63;
        floatx4 q4 = *(const floatx4*)(q_in + idx);
        floatx4 k4 = *(const floatx4*)(k_in + idx);
        floatx4 wq4 = *(const floatx4*)(wq + c);
        floatx4 bq4 = *(const floatx4*)(bq + c);
        floatx4 wk4 = *(const floatx4*)(wk + c);
        floatx4 bk4 = *(const floatx4*)(bk + c);
        const float qsc = 0.125f * LOG2E;
        half4 qh, kh;
        qh[0] = (_Float16)((q4.x * wq4.x + bq4.x) * qsc);
        qh[1] = (_Float16)((q4.y * wq4.y + bq4.y) * qsc);
        qh[2] = (_Float16)((q4.z * wq4.z + bq4.z) * qsc);
        qh[3] = (_Float16)((q4.w * wq4.w + bq4.w) * qsc);
        kh[0] = (_Float16)(k4.x * wk4.x + bk4.x);
        kh[1] = (_Float16)(k4.y * wk4.y + bk4.y);
        kh[2] = (_Float16)(k4.z * wk4.z + bk4.z);
        kh[3] = (_Float16)(k4.w * wk4.w + bk4.w);
        size_t o = ((size_t)(b * NH + h) * HW + row) * DH + ch;
        *(half4*)(Qhat + o) = qh;
        *(half4*)(Khat + o) = kh;
    } else {
        __shared__ _Float16 Lt[64 * 68];
        int bx = blockIdx.x - 4096;
        int t = threadIdx.x;
        int key0 = (bx & 63) * 64;
        int bh = bx >> 6;
        int b = bh >> 2, h = bh & 3;
        int c4 = (t & 15) * 4;
        floatx4 wv4 = *(const floatx4*)(wv + h * DH + c4);
        floatx4 bv4 = *(const floatx4*)(bv + h * DH + c4);
        #pragma unroll
        for (int p = 0; p < 4; ++p) {
            int key = p * 16 + (t >> 4);
            const float* vp = v_in + ((size_t)b * HW + key0 + key) * CCH + h * DH + c4;
            floatx4 v4 = *(const floatx4*)vp;
            half4 vh;
            vh[0] = (_Float16)(v4.x * wv4.x + bv4.x);
            vh[1] = (_Float16)(v4.y * wv4.y + bv4.y);
            vh[2] = (_Float16)(v4.z * wv4.z + bv4.z);
            vh[3] = (_Float16)(v4.w * wv4.w + bv4.w);
            *(half4*)(&Lt[key * 68 + c4]) = vh;
        }
        __syncthreads();
        #pragma unroll
        for (int p = 0; p < 2; ++p) {
            int ch = p * 32 + (t >> 3);
            int kg = (t & 7) * 8;
            half8 v8;
            #pragma unroll
            for (int j = 0; j < 8; ++j) v8[j] = Lt[(kg + j) * 68 + ch];
            *(half8*)(Vthat + ((size_t)bh * DH + ch) * HW + key0 + kg) = v8;
        }
    }
}

// ---------- attention (transposed, register-P, K-parity-split 8-wave) ----------
__launch_bounds__(512, 4)
__global__ void attn_kernel(
    const _Float16* __restrict__ Qhat, const _Float16* __restrict__ Khat,
    const _Float16* __restrict__ Vthat,
    const float* __restrict__ wp, const float* __restrict__ bp,
    float* __restrict__ out)
{
    // pool: set0 {Kev 8K | Kod 8K | Vev 8K | Vod 8K} | set1 {same} = 64KB
    // epilogue reuses: P1 partials 32KB @0, m/l @32768, Ot @0
    __shared__ alignas(16) char pool[65536];

    const int tid = threadIdx.x;
    const int wave = tid >> 6;      // 0..7
    const int lane = tid & 63;
    const int l15 = lane & 15;
    const int quad = lane >> 4;
    const int ksw = l15 & 7;
    const int qw = wave & 3;        // q-group 0..3 (32 rows each)
    const int par = wave >> 2;      // K-tile parity: 0=even tiles, 1=odd tiles

    const int qtile = blockIdx.x;
    const int bh = blockIdx.y;

    // Q B-frags: B[k=ch][n=q], lane holds ch = quad*8+j (+32), q = l15 (+16g)
    const int q0 = qtile * QTILE + qw * 32;
    half8 qfrag[2][2];
    #pragma unroll
    for (int g = 0; g < 2; ++g) {
        const _Float16* qp = Qhat + ((size_t)bh * HW + q0 + g * 16 + l15) * DH + quad * 8;
        qfrag[g][0] = *(const half8*)(qp);
        qfrag[g][1] = *(const half8*)(qp + 32);
    }

    // staging lane addresses (XOR swizzle of 8-half groups in global addr)
    // 8 waves x 8 rows cover a 64-row tile; 2 issues cover the 128-row pair
    const int srow0 = lane >> 3;
    const int sw = (lane & 7) ^ srow0;
    const _Float16* kgp = Khat + ((size_t)bh * HW + wave * 8 + srow0) * DH + sw * 8;
    const _Float16* vgp = Vthat + ((size_t)bh * DH + wave * 8 + srow0) * HW + sw * 8;

    // per-parity compute bases
    _Float16* Kp0 = (_Float16*)(pool + par * 8192);
    _Float16* Vp0 = (_Float16*)(pool + 16384 + par * 8192);
    _Float16* Kp1 = (_Float16*)(pool + 32768 + par * 8192);
    _Float16* Vp1 = (_Float16*)(pool + 32768 + 16384 + par * 8192);

    floatx4 acc[2][4];
    float m_i[2], l_i[2];
    #pragma unroll
    for (int g = 0; g < 2; ++g) {
        m_i[g] = -1e30f; l_i[g] = 0.0f;
        #pragma unroll
        for (int nt = 0; nt < 4; ++nt) { floatx4 z = {0.f,0.f,0.f,0.f}; acc[g][nt] = z; }
    }

    // stage super-tile st (K keys st*128..+127, V same) into set at byte soff
    #define STAGE(st, soff) do {                                               \
        const size_t koff = (size_t)(st) * 128 * DH;                           \
        const size_t voff = (size_t)(st) * 128;                                \
        gload_lds16(kgp + koff,           pool + (soff) + wave * 1024);        \
        gload_lds16(kgp + koff + 64 * DH, pool + (soff) + 8192 + wave * 1024); \
        gload_lds16(vgp + voff,           pool + (soff) + 16384 + wave * 1024);\
        gload_lds16(vgp + voff + 64,      pool + (soff) + 24576 + wave * 1024);\
    } while (0)

    #define COMPUTE(KB, VB) do {                                               \
        floatx4 S[2][4];                                                       \
        _Pragma("unroll")                                                      \
        for (int kt = 0; kt < 4; ++kt) {                                       \
            const _Float16* kr = (KB) + (l15 + 16 * kt) * 64;                  \
            half8 kf0 = *(const half8*)(kr + ((quad ^ ksw) * 8));              \
            half8 kf1 = *(const half8*)(kr + (((4 + quad) ^ ksw) * 8));        \
            _Pragma("unroll")                                                  \
            for (int g = 0; g < 2; ++g) {                                      \
                floatx4 s = {0.f, 0.f, 0.f, 0.f};                              \
                s = mfma_k32(kf0, qfrag[g][0], s);                             \
                s = mfma_k32(kf1, qfrag[g][1], s);                             \
                S[g][kt] = s;                                                  \
            }                                                                  \
        }                                                                      \
        half4 pfrag[2][4];                                                     \
        _Pragma("unroll")                                                      \
        for (int g = 0; g < 2; ++g) {                                          \
            float mx = fmaxf(fmaxf(fmaxf(S[g][0][0], S[g][0][1]),              \
                                   fmaxf(S[g][0][2], S[g][0][3])),             \
                             fmaxf(fmaxf(S[g][1][0], S[g][1][1]),              \
                                   fmaxf(S[g][1][2], S[g][1][3])));            \
            float mx2 = fmaxf(fmaxf(fmaxf(S[g][2][0], S[g][2][1]),             \
                                    fmaxf(S[g][2][2], S[g][2][3])),            \
                              fmaxf(fmaxf(S[g][3][0], S[g][3][1]),             \
                                    fmaxf(S[g][3][2], S[g][3][3])));           \
            mx = fmaxf(mx, mx2);                                               \
            mx = fmaxf(mx, __shfl_xor(mx, 16));                                \
            mx = fmaxf(mx, __shfl_xor(mx, 32));                                \
            float nm = fmaxf(m_i[g], mx);                                      \
            float alpha = __builtin_amdgcn_exp2f(m_i[g] - nm);                 \
            float rs = 0.0f;                                                   \
            _Pragma("unroll")                                                  \
            for (int kt = 0; kt < 4; ++kt) {                                   \
                float p0 = __builtin_amdgcn_exp2f(S[g][kt][0] - nm);           \
                float p1 = __builtin_amdgcn_exp2f(S[g][kt][1] - nm);           \
                float p2 = __builtin_amdgcn_exp2f(S[g][kt][2] - nm);           \
                float p3 = __builtin_amdgcn_exp2f(S[g][kt][3] - nm);           \
                rs += (p0 + p1) + (p2 + p3);                                   \
                pk16x2 lo = __builtin_amdgcn_cvt_pkrtz(p0, p1);                \
                pk16x2 hi = __builtin_amdgcn_cvt_pkrtz(p2, p3);                \
                half4 pk;                                                      \
                pk[0] = (_Float16)lo[0]; pk[1] = (_Float16)lo[1];              \
                pk[2] = (_Float16)hi[0]; pk[3] = (_Float16)hi[1];              \
                pfrag[g][kt] = pk;                                             \
            }                                                                  \
            rs += __shfl_xor(rs, 16);                                          \
            rs += __shfl_xor(rs, 32);                                          \
            l_i[g] = l_i[g] * alpha + rs;                                      \
            m_i[g] = nm;                                                       \
            _Pragma("unroll")                                                  \
            for (int nt = 0; nt < 4; ++nt) acc[g][nt] *= alpha;                \
        }                                                                      \
        _Pragma("unroll")                                                      \
        for (int kt = 0; kt < 4; ++kt) {                                       \
            _Pragma("unroll")                                                  \
            for (int nt = 0; nt < 4; ++nt) {                                   \
                const _Float16* vr = (VB) + (l15 + 16 * nt) * 64               \
                    + (((2 * kt + (quad >> 1)) ^ ksw) * 8) + (quad & 1) * 4;   \
                half4 vf = *(const half4*)vr;                                  \
                acc[0][nt] = mfma_k16(vf, pfrag[0][kt], acc[0][nt]);           \
                acc[1][nt] = mfma_k16(vf, pfrag[1][kt], acc[1][nt]);           \
            }                                                                  \
        }                                                                      \
    } while (0)

    STAGE(0, 0);
    for (int st = 0; st < NST; st += 2) {
        __syncthreads();
        if (st + 1 < NST) STAGE(st + 1, 32768);
        COMPUTE(Kp0, Vp0);
        __syncthreads();
        if (st + 2 < NST) STAGE(st + 2, 0);
        COMPUTE(Kp1, Vp1);
    }

    // ---- epilogue: merge K-parity partials, then transpose + store ----
    const int b = bh >> 2, h = bh & 3, ch0 = h * DH;
    float* P1 = (float*)pool;                    // [4 qw][32 q][64 ch] f32 = 32KB
    float* Pm = (float*)(pool + 32768);          // [4 qw][32 q]
    float* Pl = (float*)(pool + 33792);

    __syncthreads();
    if (par == 1) {
        #pragma unroll
        for (int g = 0; g < 2; ++g) {
            #pragma unroll
            for (int nt = 0; nt < 4; ++nt)
                *(floatx4*)&P1[qw * 2048 + (g * 16 + l15) * 64 + nt * 16 + quad * 4] = acc[g][nt];
            if (quad == 0) {
                Pm[qw * 32 + g * 16 + l15] = m_i[g];
                Pl[qw * 32 + g * 16 + l15] = l_i[g];
            }
        }
    }
    __syncthreads();
    if (par == 0) {
        #pragma unroll
        for (int g = 0; g < 2; ++g) {
            float mB = Pm[qw * 32 + g * 16 + l15];
            float lB = Pl[qw * 32 + g * 16 + l15];
            float m = fmaxf(m_i[g], mB);
            float aA = __builtin_amdgcn_exp2f(m_i[g] - m);
            float aB = __builtin_amdgcn_exp2f(mB - m);
            float inv = 1.0f / (l_i[g] * aA + lB * aB);
            #pragma unroll
            for (int nt = 0; nt < 4; ++nt) {
                floatx4 vB = *(const floatx4*)&P1[qw * 2048 + (g * 16 + l15) * 64 + nt * 16 + quad * 4];
                #pragma unroll
                for (int r = 0; r < 4; ++r)
                    acc[g][nt][r] = (acc[g][nt][r] * aA + vB[r] * aB) * inv;
            }
        }
    }
    __syncthreads();
    if (par == 0) {
        floatx4 wp4 = *(const floatx4*)(wp + ch0 + l15 * 4);
        floatx4 bp4 = *(const floatx4*)(bp + ch0 + l15 * 4);
        float* Ot = (float*)(pool) + qw * 2304;   // [32 q][72] floats, 9216B/wave
        #pragma unroll
        for (int g = 0; g < 2; ++g) {
            #pragma unroll
            for (int nt = 0; nt < 4; ++nt)
                *(floatx4*)&Ot[(g * 16 + l15) * 72 + nt * 16 + quad * 4] = acc[g][nt];
        }
        #pragma unroll
        for (int i = 0; i < 8; ++i) {
            int q = i * 4 + quad;
            floatx4 v = *(const floatx4*)&Ot[q * 72 + l15 * 4];
            floatx4 o;
            o.x = v.x * wp4.x + bp4.x;
            o.y = v.y * wp4.y + bp4.y;
            o.z = v.z * wp4.z + bp4.z;
            o.w = v.w * wp4.w + bp4.w;
            *(floatx4*)(out + ((size_t)b * HW + q0 + q) * CCH + ch0 + l15 * 4) = o;
        }
    }
    #undef STAGE
    #undef COMPUTE
}

extern "C" void kernel_launch(void* const* d_in, const int* in_sizes, int n_in,
                              void* d_out, int out_size, void* d_ws, size_t ws_size,
                              hipStream_t stream) {
    const float* q_in = (const float*)d_in[0];
    const float* k_in = (const float*)d_in[1];
    const float* v_in = (const float*)d_in[2];
    const float* wq = (const float*)d_in[3];
    const float* bq = (const float*)d_in[4];
    const float* wk = (const float*)d_in[5];
    const float* bk = (const float*)d_in[6];
    const float* wv = (const float*)d_in[7];
    const float* bv = (const float*)d_in[8];
    const float* wp = (const float*)d_in[9];
    const float* bp = (const float*)d_in[10];
    float* out = (float*)d_out;

    const size_t tensor_halves = (size_t)4 * NH * HW * DH;
    _Float16* Qhat = (_Float16*)d_ws;
    _Float16* Khat = Qhat + tensor_halves;
    _Float16* Vthat = Khat + tensor_halves;

    prepass_all<<<dim3(4096 + 1024), 256, 0, stream>>>(
        q_in, k_in, v_in, wq, bq, wk, bk, wv, bv, Qhat, Khat, Vthat);
    attn_kernel<<<dim3(HW / QTILE, 4 * NH), 512, 0, stream>>>(
        Qhat, Khat, Vthat, wp, bp, out);
}

// Round 3
// 118.165 us; speedup vs baseline: 1.1071x; 1.0950x over previous
//
#include <hip/hip_runtime.h>

// SpatialAttention B=4 HW=4096 C=256 NH=4 d=64 — f16 MFMA flash attention.
// R8 (= R5 + VALU diet): R6/R7 proved time is invariant to occupancy (both
// doubled waves/SIMD, all counters frozen) -> per-CU issue/pipe throughput
// bound, VALU dominant. Keep R5's 4-wave structure; cut softmax VALU:
//  (1) l-sum via MFMA ones-column (kills 32 fadd + 4 shfl + 2 fma per tile),
//  (2) defer-max THR=8: skip alpha exp2 + 33-mul rescale when max stable,
//  (3) v_max3 3-ary max tree (15 -> 8 ops per g).

#define HW 4096
#define CCH 256
#define DH 64
#define NH 4
#define QTILE 128
#define KTILE 64
#define NKT (HW / KTILE)
#define LOG2E 1.44269504088896340736f

typedef __attribute__((ext_vector_type(8))) _Float16 half8;
typedef __attribute__((ext_vector_type(4))) _Float16 half4;
typedef __attribute__((ext_vector_type(2))) __fp16 pk16x2;   // cvt_pkrtz native type
typedef __attribute__((ext_vector_type(4))) float floatx4;

typedef __attribute__((address_space(1))) const unsigned int gbl_u32;
typedef __attribute__((address_space(3))) unsigned int lds_u32;

__device__ __forceinline__ void gload_lds16(const void* g, void* l) {
    __builtin_amdgcn_global_load_lds((gbl_u32*)g, (lds_u32*)l, 16, 0, 0);
}
__device__ __forceinline__ floatx4 mfma_k32(half8 a, half8 b, floatx4 c) {
    return __builtin_amdgcn_mfma_f32_16x16x32_f16(a, b, c, 0, 0, 0);
}
__device__ __forceinline__ floatx4 mfma_k16(half4 a, half4 b, floatx4 c) {
    return __builtin_amdgcn_mfma_f32_16x16x16f16(a, b, c, 0, 0, 0);
}
__device__ __forceinline__ float max3f(float a, float b, float c) {
    return fmaxf(fmaxf(a, b), c);   // clang fuses to v_max3_f32
}

// ---------- fused prepass ----------
// blocks [0,4096): Qhat/Khat elementwise (scale*log2e folded into Q)
// blocks [4096,5120): Vthat transpose [B*NH][64][HW]
__global__ __launch_bounds__(256) void prepass_all(
    const float* __restrict__ q_in, const float* __restrict__ k_in,
    const float* __restrict__ v_in,
    const float* __restrict__ wq, const float* __restrict__ bq,
    const float* __restrict__ wk, const float* __restrict__ bk,
    const float* __restrict__ wv, const float* __restrict__ bv,
    _Float16* __restrict__ Qhat, _Float16* __restrict__ Khat,
    _Float16* __restrict__ Vthat)
{
    if (blockIdx.x < 4096) {
        int idx = (blockIdx.x * 256 + threadIdx.x) * 4;
        int b = idx >> 20;
        int rem = idx & ((1 << 20) - 1);
        int row = rem >> 8;
        int c = rem & 255;
        int h = c >> 6;
        int ch = c & 63;
        floatx4 q4 = *(const floatx4*)(q_in + idx);
        floatx4 k4 = *(const floatx4*)(k_in + idx);
        floatx4 wq4 = *(const floatx4*)(wq + c);
        floatx4 bq4 = *(const floatx4*)(bq + c);
        floatx4 wk4 = *(const floatx4*)(wk + c);
        floatx4 bk4 = *(const floatx4*)(bk + c);
        const float qsc = 0.125f * LOG2E;
        half4 qh, kh;
        qh[0] = (_Float16)((q4.x * wq4.x + bq4.x) * qsc);
        qh[1] = (_Float16)((q4.y * wq4.y + bq4.y) * qsc);
        qh[2] = (_Float16)((q4.z * wq4.z + bq4.z) * qsc);
        qh[3] = (_Float16)((q4.w * wq4.w + bq4.w) * qsc);
        kh[0] = (_Float16)(k4.x * wk4.x + bk4.x);
        kh[1] = (_Float16)(k4.y * wk4.y + bk4.y);
        kh[2] = (_Float16)(k4.z * wk4.z + bk4.z);
        kh[3] = (_Float16)(k4.w * wk4.w + bk4.w);
        size_t o = ((size_t)(b * NH + h) * HW + row) * DH + ch;
        *(half4*)(Qhat + o) = qh;
        *(half4*)(Khat + o) = kh;
    } else {
        __shared__ _Float16 Lt[64 * 68];
        int bx = blockIdx.x - 4096;
        int t = threadIdx.x;
        int key0 = (bx & 63) * 64;
        int bh = bx >> 6;
        int b = bh >> 2, h = bh & 3;
        int c4 = (t & 15) * 4;
        floatx4 wv4 = *(const floatx4*)(wv + h * DH + c4);
        floatx4 bv4 = *(const floatx4*)(bv + h * DH + c4);
        #pragma unroll
        for (int p = 0; p < 4; ++p) {
            int key = p * 16 + (t >> 4);
            const float* vp = v_in + ((size_t)b * HW + key0 + key) * CCH + h * DH + c4;
            floatx4 v4 = *(const floatx4*)vp;
            half4 vh;
            vh[0] = (_Float16)(v4.x * wv4.x + bv4.x);
            vh[1] = (_Float16)(v4.y * wv4.y + bv4.y);
            vh[2] = (_Float16)(v4.z * wv4.z + bv4.z);
            vh[3] = (_Float16)(v4.w * wv4.w + bv4.w);
            *(half4*)(&Lt[key * 68 + c4]) = vh;
        }
        __syncthreads();
        #pragma unroll
        for (int p = 0; p < 2; ++p) {
            int ch = p * 32 + (t >> 3);
            int kg = (t & 7) * 8;
            half8 v8;
            #pragma unroll
            for (int j = 0; j < 8; ++j) v8[j] = Lt[(kg + j) * 68 + ch];
            *(half8*)(Vthat + ((size_t)bh * DH + ch) * HW + key0 + kg) = v8;
        }
    }
}

// ---------- attention (transposed, register-P) ----------
__launch_bounds__(256, 3)
__global__ void attn_kernel(
    const _Float16* __restrict__ Qhat, const _Float16* __restrict__ Khat,
    const _Float16* __restrict__ Vthat,
    const float* __restrict__ wp, const float* __restrict__ bp,
    float* __restrict__ out)
{
    // pool: Ksm0 | Ksm1 | Vsm0 | Vsm1 (8KB each); epilogue reuses as Ot
    __shared__ alignas(16) char pool[36864];
    _Float16* Ksm0 = (_Float16*)(pool);
    _Float16* Ksm1 = (_Float16*)(pool + 8192);
    _Float16* Vsm0 = (_Float16*)(pool + 16384);
    _Float16* Vsm1 = (_Float16*)(pool + 24576);

    const int tid = threadIdx.x;
    const int wave = tid >> 6;
    const int lane = tid & 63;
    const int l15 = lane & 15;
    const int quad = lane >> 4;
    const int ksw = l15 & 7;

    const int qtile = blockIdx.x;
    const int bh = blockIdx.y;

    // Q B-frags: B[k=ch][n=q], lane holds ch = quad*8+j (+32), q = l15 (+16g)
    const int q0 = qtile * QTILE + wave * 32;
    half8 qfrag[2][2];
    #pragma unroll
    for (int g = 0; g < 2; ++g) {
        const _Float16* qp = Qhat + ((size_t)bh * HW + q0 + g * 16 + l15) * DH + quad * 8;
        qfrag[g][0] = *(const half8*)(qp);
        qfrag[g][1] = *(const half8*)(qp + 32);
    }

    // staging lane addresses (XOR swizzle of 8-half groups in global addr)
    const int srow0 = lane >> 3;
    const int sw = (lane & 7) ^ srow0;
    const _Float16* kgp0 = Khat + ((size_t)bh * HW + wave * 8 + srow0) * DH + sw * 8;
    const _Float16* kgp1 = kgp0 + (size_t)32 * DH;
    const _Float16* vgp0 = Vthat + ((size_t)bh * DH + wave * 8 + srow0) * HW + sw * 8;
    const _Float16* vgp1 = vgp0 + (size_t)32 * HW;

    half4 ones4;
    ones4[0] = ones4[1] = ones4[2] = ones4[3] = (_Float16)1.0f;

    floatx4 acc[2][4];
    floatx4 accl[2];                 // l-sum accumulator (ones-column); [0] used
    float m_i[2];
    #pragma unroll
    for (int g = 0; g < 2; ++g) {
        m_i[g] = -1e30f;
        floatx4 z = {0.f,0.f,0.f,0.f};
        accl[g] = z;
        #pragma unroll
        for (int nt = 0; nt < 4; ++nt) acc[g][nt] = z;
    }

    #define STAGE(kt, KB, VB) do {                                             \
        gload_lds16(kgp0 + (size_t)(kt) * (KTILE * DH), (KB) + wave * 512);    \
        gload_lds16(kgp1 + (size_t)(kt) * (KTILE * DH), (KB) + 2048 + wave * 512); \
        gload_lds16(vgp0 + (size_t)(kt) * KTILE, (VB) + wave * 512);           \
        gload_lds16(vgp1 + (size_t)(kt) * KTILE, (VB) + 2048 + wave * 512);    \
    } while (0)

    #define COMPUTE(KB, VB) do {                                               \
        floatx4 S[2][4];                                                       \
        _Pragma("unroll")                                                      \
        for (int kt = 0; kt < 4; ++kt) {                                       \
            const _Float16* kr = (KB) + (l15 + 16 * kt) * 64;                  \
            half8 kf0 = *(const half8*)(kr + ((quad ^ ksw) * 8));              \
            half8 kf1 = *(const half8*)(kr + (((4 + quad) ^ ksw) * 8));        \
            _Pragma("unroll")                                                  \
            for (int g = 0; g < 2; ++g) {                                      \
                floatx4 s = {0.f, 0.f, 0.f, 0.f};                              \
                s = mfma_k32(kf0, qfrag[g][0], s);                             \
                s = mfma_k32(kf1, qfrag[g][1], s);                             \
                S[g][kt] = s;                                                  \
            }                                                                  \
        }                                                                      \
        float mxa[2];                                                          \
        _Pragma("unroll")                                                      \
        for (int g = 0; g < 2; ++g) {                                          \
            float t0 = max3f(S[g][0][0], S[g][0][1], S[g][0][2]);              \
            float t1 = max3f(S[g][0][3], S[g][1][0], S[g][1][1]);              \
            float t2 = max3f(S[g][1][2], S[g][1][3], S[g][2][0]);              \
            float t3 = max3f(S[g][2][1], S[g][2][2], S[g][2][3]);              \
            float t4 = max3f(S[g][3][0], S[g][3][1], S[g][3][2]);              \
            float u0 = max3f(t0, t1, S[g][3][3]);                              \
            float u1 = fmaxf(t2, fmaxf(t3, t4));                               \
            float mx = fmaxf(u0, u1);                                          \
            mx = fmaxf(mx, __shfl_xor(mx, 16));                                \
            mx = fmaxf(mx, __shfl_xor(mx, 32));                                \
            mxa[g] = mx;                                                       \
        }                                                                      \
        bool ok = (mxa[0] <= m_i[0] + 8.0f) && (mxa[1] <= m_i[1] + 8.0f);      \
        if (!__all(ok)) {                                                      \
            _Pragma("unroll")                                                  \
            for (int g = 0; g < 2; ++g) {                                      \
                float nm = fmaxf(m_i[g], mxa[g]);                              \
                float alpha = __builtin_amdgcn_exp2f(m_i[g] - nm);             \
                accl[g][0] *= alpha;                                           \
                _Pragma("unroll")                                              \
                for (int nt = 0; nt < 4; ++nt) acc[g][nt] *= alpha;            \
                m_i[g] = nm;                                                   \
            }                                                                  \
        }                                                                      \
        half4 pfrag[2][4];                                                     \
        _Pragma("unroll")                                                      \
        for (int g = 0; g < 2; ++g) {                                          \
            float nm = m_i[g];                                                 \
            _Pragma("unroll")                                                  \
            for (int kt = 0; kt < 4; ++kt) {                                   \
                float p0 = __builtin_amdgcn_exp2f(S[g][kt][0] - nm);           \
                float p1 = __builtin_amdgcn_exp2f(S[g][kt][1] - nm);           \
                float p2 = __builtin_amdgcn_exp2f(S[g][kt][2] - nm);           \
                float p3 = __builtin_amdgcn_exp2f(S[g][kt][3] - nm);           \
                pk16x2 lo = __builtin_amdgcn_cvt_pkrtz(p0, p1);                \
                pk16x2 hi = __builtin_amdgcn_cvt_pkrtz(p2, p3);                \
                half4 pk;                                                      \
                pk[0] = (_Float16)lo[0]; pk[1] = (_Float16)lo[1];              \
                pk[2] = (_Float16)hi[0]; pk[3] = (_Float16)hi[1];              \
                pfrag[g][kt] = pk;                                             \
            }                                                                  \
        }                                                                      \
        _Pragma("unroll")                                                      \
        for (int kt = 0; kt < 4; ++kt) {                                       \
            accl[0] = mfma_k16(ones4, pfrag[0][kt], accl[0]);                  \
            accl[1] = mfma_k16(ones4, pfrag[1][kt], accl[1]);                  \
            _Pragma("unroll")                                                  \
            for (int nt = 0; nt < 4; ++nt) {                                   \
                const _Float16* vr = (VB) + (l15 + 16 * nt) * 64               \
                    + (((2 * kt + (quad >> 1)) ^ ksw) * 8) + (quad & 1) * 4;   \
                half4 vf = *(const half4*)vr;                                  \
                acc[0][nt] = mfma_k16(vf, pfrag[0][kt], acc[0][nt]);           \
                acc[1][nt] = mfma_k16(vf, pfrag[1][kt], acc[1][nt]);           \
            }                                                                  \
        }                                                                      \
    } while (0)

    STAGE(0, Ksm0, Vsm0);
    for (int kt = 0; kt < NKT; kt += 2) {
        __syncthreads();
        if (kt + 1 < NKT) STAGE(kt + 1, Ksm1, Vsm1);
        COMPUTE(Ksm0, Vsm0);
        __syncthreads();
        if (kt + 2 < NKT) STAGE(kt + 2, Ksm0, Vsm0);
        COMPUTE(Ksm1, Vsm1);
    }

    // ---- epilogue: transpose O^T through LDS, coalesced stores ----
    const int b = bh >> 2, h = bh & 3, ch0 = h * DH;
    floatx4 wp4 = *(const floatx4*)(wp + ch0 + l15 * 4);
    floatx4 bp4 = *(const floatx4*)(bp + ch0 + l15 * 4);
    float inv_l[2];
    #pragma unroll
    for (int g = 0; g < 2; ++g) inv_l[g] = 1.0f / accl[g][0];

    __syncthreads();
    float* Ot = (float*)(pool) + wave * 2304;   // [32 q][72] floats, 9216B/wave
    #pragma unroll
    for (int g = 0; g < 2; ++g) {
        #pragma unroll
        for (int nt = 0; nt < 4; ++nt) {
            floatx4 o;
            #pragma unroll
            for (int r = 0; r < 4; ++r) o[r] = acc[g][nt][r] * inv_l[g];
            *(floatx4*)&Ot[(g * 16 + l15) * 72 + nt * 16 + quad * 4] = o;
        }
    }
    #pragma unroll
    for (int i = 0; i < 8; ++i) {
        int q = i * 4 + quad;
        floatx4 v = *(const floatx4*)&Ot[q * 72 + l15 * 4];
        floatx4 o;
        o.x = v.x * wp4.x + bp4.x;
        o.y = v.y * wp4.y + bp4.y;
        o.z = v.z * wp4.z + bp4.z;
        o.w = v.w * wp4.w + bp4.w;
        *(floatx4*)(out + ((size_t)b * HW + q0 + q) * CCH + ch0 + l15 * 4) = o;
    }
    #undef STAGE
    #undef COMPUTE
}

extern "C" void kernel_launch(void* const* d_in, const int* in_sizes, int n_in,
                              void* d_out, int out_size, void* d_ws, size_t ws_size,
                              hipStream_t stream) {
    const float* q_in = (const float*)d_in[0];
    const float* k_in = (const float*)d_in[1];
    const float* v_in = (const float*)d_in[2];
    const float* wq = (const float*)d_in[3];
    const float* bq = (const float*)d_in[4];
    const float* wk = (const float*)d_in[5];
    const float* bk = (const float*)d_in[6];
    const float* wv = (const float*)d_in[7];
    const float* bv = (const float*)d_in[8];
    const float* wp = (const float*)d_in[9];
    const float* bp = (const float*)d_in[10];
    float* out = (float*)d_out;

    const size_t tensor_halves = (size_t)4 * NH * HW * DH;
    _Float16* Qhat = (_Float16*)d_ws;
    _Float16* Khat = Qhat + tensor_halves;
    _Float16* Vthat = Khat + tensor_halves;

    prepass_all<<<dim3(4096 + 1024), 256, 0, stream>>>(
        q_in, k_in, v_in, wq, bq, wk, bk, wv, bv, Qhat, Khat, Vthat);
    attn_kernel<<<dim3(HW / QTILE, 4 * NH), 256, 0, stream>>>(
        Qhat, Khat, Vthat, wp, bp, out);
}

// Round 4
// 105.982 us; speedup vs baseline: 1.2343x; 1.1150x over previous
//
#include <hip/hip_runtime.h>

// SpatialAttention B=4 HW=4096 C=256 NH=4 d=64 — f16 MFMA flash attention.
// R9 (= R8 + full-k32 PV): MfmaUtil delta in R8 (+19% for +8 k16) showed
// 16x16x16 costs the SAME cycles as 16x16x32 (half per-FLOP rate) -> PV was
// burning 2x matrix cycles. Khat rows are permuted per-32-key-chunk in the
// prepass so each lane's own S registers (two 16-tiles) are exactly its k32
// B-frag keys (quad*8+j) — PV + l-sum now 20 k32 (was 40 k16), no shuffles.
// V fragments become 16B-contiguous -> 8x ds_read_b128 (was 16x b64).
// T5 setprio(1) wraps both MFMA clusters.

#define HW 4096
#define CCH 256
#define DH 64
#define NH 4
#define QTILE 128
#define KTILE 64
#define NKT (HW / KTILE)
#define LOG2E 1.44269504088896340736f

typedef __attribute__((ext_vector_type(8))) _Float16 half8;
typedef __attribute__((ext_vector_type(4))) _Float16 half4;
typedef __attribute__((ext_vector_type(2))) __fp16 pk16x2;   // cvt_pkrtz native type
typedef __attribute__((ext_vector_type(4))) float floatx4;

typedef __attribute__((address_space(1))) const unsigned int gbl_u32;
typedef __attribute__((address_space(3))) unsigned int lds_u32;

__device__ __forceinline__ void gload_lds16(const void* g, void* l) {
    __builtin_amdgcn_global_load_lds((gbl_u32*)g, (lds_u32*)l, 16, 0, 0);
}
__device__ __forceinline__ floatx4 mfma_k32(half8 a, half8 b, floatx4 c) {
    return __builtin_amdgcn_mfma_f32_16x16x32_f16(a, b, c, 0, 0, 0);
}
__device__ __forceinline__ float max3f(float a, float b, float c) {
    return fmaxf(fmaxf(a, b), c);   // clang fuses to v_max3_f32
}

// ---------- fused prepass ----------
// blocks [0,4096): Qhat/Khat elementwise (scale*log2e folded into Q).
// Khat rows are permuted within each 32-key chunk: physical key p sits at
// slot s where pi(s)=p, pi(s<16)=8*(s>>2)+(s&3), pi(s>=16)=8*((s>>2)&3)+4+(s&3).
// This makes the QK^T C/D row map (quad*4+r over two 16-tiles) coincide with
// the k32 PV B-frag k-map (quad*8+j) with zero cross-lane traffic.
// blocks [4096,5120): Vthat transpose [B*NH][64][HW] (physical key order)
__global__ __launch_bounds__(256) void prepass_all(
    const float* __restrict__ q_in, const float* __restrict__ k_in,
    const float* __restrict__ v_in,
    const float* __restrict__ wq, const float* __restrict__ bq,
    const float* __restrict__ wk, const float* __restrict__ bk,
    const float* __restrict__ wv, const float* __restrict__ bv,
    _Float16* __restrict__ Qhat, _Float16* __restrict__ Khat,
    _Float16* __restrict__ Vthat)
{
    if (blockIdx.x < 4096) {
        int idx = (blockIdx.x * 256 + threadIdx.x) * 4;
        int b = idx >> 20;
        int rem = idx & ((1 << 20) - 1);
        int row = rem >> 8;
        int c = rem & 255;
        int h = c >> 6;
        int ch = c & 63;
        floatx4 q4 = *(const floatx4*)(q_in + idx);
        floatx4 k4 = *(const floatx4*)(k_in + idx);
        floatx4 wq4 = *(const floatx4*)(wq + c);
        floatx4 bq4 = *(const floatx4*)(bq + c);
        floatx4 wk4 = *(const floatx4*)(wk + c);
        floatx4 bk4 = *(const floatx4*)(bk + c);
        const float qsc = 0.125f * LOG2E;
        half4 qh, kh;
        qh[0] = (_Float16)((q4.x * wq4.x + bq4.x) * qsc);
        qh[1] = (_Float16)((q4.y * wq4.y + bq4.y) * qsc);
        qh[2] = (_Float16)((q4.z * wq4.z + bq4.z) * qsc);
        qh[3] = (_Float16)((q4.w * wq4.w + bq4.w) * qsc);
        kh[0] = (_Float16)(k4.x * wk4.x + bk4.x);
        kh[1] = (_Float16)(k4.y * wk4.y + bk4.y);
        kh[2] = (_Float16)(k4.z * wk4.z + bk4.z);
        kh[3] = (_Float16)(k4.w * wk4.w + bk4.w);
        size_t o_q = ((size_t)(b * NH + h) * HW + row) * DH + ch;
        // K row permutation within the 32-key chunk (see header comment)
        int p = row & 31;
        int srow = ((p & 4) << 2) + ((p >> 3) << 2) + (p & 3);
        int row_k = (row & ~31) | srow;
        size_t o_k = ((size_t)(b * NH + h) * HW + row_k) * DH + ch;
        *(half4*)(Qhat + o_q) = qh;
        *(half4*)(Khat + o_k) = kh;
    } else {
        __shared__ _Float16 Lt[64 * 68];
        int bx = blockIdx.x - 4096;
        int t = threadIdx.x;
        int key0 = (bx & 63) * 64;
        int bh = bx >> 6;
        int b = bh >> 2, h = bh & 3;
        int c4 = (t & 15) * 4;
        floatx4 wv4 = *(const floatx4*)(wv + h * DH + c4);
        floatx4 bv4 = *(const floatx4*)(bv + h * DH + c4);
        #pragma unroll
        for (int p = 0; p < 4; ++p) {
            int key = p * 16 + (t >> 4);
            const float* vp = v_in + ((size_t)b * HW + key0 + key) * CCH + h * DH + c4;
            floatx4 v4 = *(const floatx4*)vp;
            half4 vh;
            vh[0] = (_Float16)(v4.x * wv4.x + bv4.x);
            vh[1] = (_Float16)(v4.y * wv4.y + bv4.y);
            vh[2] = (_Float16)(v4.z * wv4.z + bv4.z);
            vh[3] = (_Float16)(v4.w * wv4.w + bv4.w);
            *(half4*)(&Lt[key * 68 + c4]) = vh;
        }
        __syncthreads();
        #pragma unroll
        for (int p = 0; p < 2; ++p) {
            int ch = p * 32 + (t >> 3);
            int kg = (t & 7) * 8;
            half8 v8;
            #pragma unroll
            for (int j = 0; j < 8; ++j) v8[j] = Lt[(kg + j) * 68 + ch];
            *(half8*)(Vthat + ((size_t)bh * DH + ch) * HW + key0 + kg) = v8;
        }
    }
}

// ---------- attention (transposed, register-P, all-k32) ----------
__launch_bounds__(256, 3)
__global__ void attn_kernel(
    const _Float16* __restrict__ Qhat, const _Float16* __restrict__ Khat,
    const _Float16* __restrict__ Vthat,
    const float* __restrict__ wp, const float* __restrict__ bp,
    float* __restrict__ out)
{
    // pool: Ksm0 | Ksm1 | Vsm0 | Vsm1 (8KB each); epilogue reuses as Ot
    __shared__ alignas(16) char pool[36864];
    _Float16* Ksm0 = (_Float16*)(pool);
    _Float16* Ksm1 = (_Float16*)(pool + 8192);
    _Float16* Vsm0 = (_Float16*)(pool + 16384);
    _Float16* Vsm1 = (_Float16*)(pool + 24576);

    const int tid = threadIdx.x;
    const int wave = tid >> 6;
    const int lane = tid & 63;
    const int l15 = lane & 15;
    const int quad = lane >> 4;
    const int ksw = l15 & 7;

    const int qtile = blockIdx.x;
    const int bh = blockIdx.y;

    // Q B-frags: B[k=ch][n=q], lane holds ch = quad*8+j (+32), q = l15 (+16g)
    const int q0 = qtile * QTILE + wave * 32;
    half8 qfrag[2][2];
    #pragma unroll
    for (int g = 0; g < 2; ++g) {
        const _Float16* qp = Qhat + ((size_t)bh * HW + q0 + g * 16 + l15) * DH + quad * 8;
        qfrag[g][0] = *(const half8*)(qp);
        qfrag[g][1] = *(const half8*)(qp + 32);
    }

    // staging lane addresses (XOR swizzle of 8-half groups in global addr)
    const int srow0 = lane >> 3;
    const int sw = (lane & 7) ^ srow0;
    const _Float16* kgp0 = Khat + ((size_t)bh * HW + wave * 8 + srow0) * DH + sw * 8;
    const _Float16* kgp1 = kgp0 + (size_t)32 * DH;
    const _Float16* vgp0 = Vthat + ((size_t)bh * DH + wave * 8 + srow0) * HW + sw * 8;
    const _Float16* vgp1 = vgp0 + (size_t)32 * HW;

    half8 ones8;
    #pragma unroll
    for (int j = 0; j < 8; ++j) ones8[j] = (_Float16)1.0f;

    floatx4 acc[2][4];
    floatx4 accl[2];                 // l-sum accumulator (ones-row MFMA); [0] used
    float m_i[2];
    #pragma unroll
    for (int g = 0; g < 2; ++g) {
        m_i[g] = -1e30f;
        floatx4 z = {0.f,0.f,0.f,0.f};
        accl[g] = z;
        #pragma unroll
        for (int nt = 0; nt < 4; ++nt) acc[g][nt] = z;
    }

    #define STAGE(kt, KB, VB) do {                                             \
        gload_lds16(kgp0 + (size_t)(kt) * (KTILE * DH), (KB) + wave * 512);    \
        gload_lds16(kgp1 + (size_t)(kt) * (KTILE * DH), (KB) + 2048 + wave * 512); \
        gload_lds16(vgp0 + (size_t)(kt) * KTILE, (VB) + wave * 512);           \
        gload_lds16(vgp1 + (size_t)(kt) * KTILE, (VB) + 2048 + wave * 512);    \
    } while (0)

    #define COMPUTE(KB, VB) do {                                               \
        floatx4 S[2][4];                                                       \
        __builtin_amdgcn_s_setprio(1);                                         \
        _Pragma("unroll")                                                      \
        for (int kt = 0; kt < 4; ++kt) {                                       \
            const _Float16* kr = (KB) + (l15 + 16 * kt) * 64;                  \
            half8 kf0 = *(const half8*)(kr + ((quad ^ ksw) * 8));              \
            half8 kf1 = *(const half8*)(kr + (((4 + quad) ^ ksw) * 8));        \
            _Pragma("unroll")                                                  \
            for (int g = 0; g < 2; ++g) {                                      \
                floatx4 s = {0.f, 0.f, 0.f, 0.f};                              \
                s = mfma_k32(kf0, qfrag[g][0], s);                             \
                s = mfma_k32(kf1, qfrag[g][1], s);                             \
                S[g][kt] = s;                                                  \
            }                                                                  \
        }                                                                      \
        __builtin_amdgcn_s_setprio(0);                                         \
        float mxa[2];                                                          \
        _Pragma("unroll")                                                      \
        for (int g = 0; g < 2; ++g) {                                          \
            float t0 = max3f(S[g][0][0], S[g][0][1], S[g][0][2]);              \
            float t1 = max3f(S[g][0][3], S[g][1][0], S[g][1][1]);              \
            float t2 = max3f(S[g][1][2], S[g][1][3], S[g][2][0]);              \
            float t3 = max3f(S[g][2][1], S[g][2][2], S[g][2][3]);              \
            float t4 = max3f(S[g][3][0], S[g][3][1], S[g][3][2]);              \
            float u0 = max3f(t0, t1, S[g][3][3]);                              \
            float u1 = fmaxf(t2, fmaxf(t3, t4));                               \
            float mx = fmaxf(u0, u1);                                          \
            mx = fmaxf(mx, __shfl_xor(mx, 16));                                \
            mx = fmaxf(mx, __shfl_xor(mx, 32));                                \
            mxa[g] = mx;                                                       \
        }                                                                      \
        bool ok = (mxa[0] <= m_i[0] + 8.0f) && (mxa[1] <= m_i[1] + 8.0f);      \
        if (!__all(ok)) {                                                      \
            _Pragma("unroll")                                                  \
            for (int g = 0; g < 2; ++g) {                                      \
                float nm = fmaxf(m_i[g], mxa[g]);                              \
                float alpha = __builtin_amdgcn_exp2f(m_i[g] - nm);             \
                accl[g][0] *= alpha;                                           \
                _Pragma("unroll")                                              \
                for (int nt = 0; nt < 4; ++nt) acc[g][nt] *= alpha;            \
                m_i[g] = nm;                                                   \
            }                                                                  \
        }                                                                      \
        half8 pfrag[2][2];                                                     \
        _Pragma("unroll")                                                      \
        for (int g = 0; g < 2; ++g) {                                          \
            float nm = m_i[g];                                                 \
            _Pragma("unroll")                                                  \
            for (int c = 0; c < 2; ++c) {                                      \
                float a0 = __builtin_amdgcn_exp2f(S[g][2*c][0] - nm);          \
                float a1 = __builtin_amdgcn_exp2f(S[g][2*c][1] - nm);          \
                float a2 = __builtin_amdgcn_exp2f(S[g][2*c][2] - nm);          \
                float a3 = __builtin_amdgcn_exp2f(S[g][2*c][3] - nm);          \
                float b0 = __builtin_amdgcn_exp2f(S[g][2*c+1][0] - nm);        \
                float b1 = __builtin_amdgcn_exp2f(S[g][2*c+1][1] - nm);        \
                float b2 = __builtin_amdgcn_exp2f(S[g][2*c+1][2] - nm);        \
                float b3 = __builtin_amdgcn_exp2f(S[g][2*c+1][3] - nm);        \
                pk16x2 p01 = __builtin_amdgcn_cvt_pkrtz(a0, a1);               \
                pk16x2 p23 = __builtin_amdgcn_cvt_pkrtz(a2, a3);               \
                pk16x2 p45 = __builtin_amdgcn_cvt_pkrtz(b0, b1);               \
                pk16x2 p67 = __builtin_amdgcn_cvt_pkrtz(b2, b3);               \
                half8 pk;                                                      \
                pk[0] = (_Float16)p01[0]; pk[1] = (_Float16)p01[1];            \
                pk[2] = (_Float16)p23[0]; pk[3] = (_Float16)p23[1];            \
                pk[4] = (_Float16)p45[0]; pk[5] = (_Float16)p45[1];            \
                pk[6] = (_Float16)p67[0]; pk[7] = (_Float16)p67[1];            \
                pfrag[g][c] = pk;                                              \
            }                                                                  \
        }                                                                      \
        __builtin_amdgcn_s_setprio(1);                                         \
        _Pragma("unroll")                                                      \
        for (int c = 0; c < 2; ++c) {                                          \
            accl[0] = mfma_k32(ones8, pfrag[0][c], accl[0]);                   \
            accl[1] = mfma_k32(ones8, pfrag[1][c], accl[1]);                   \
            _Pragma("unroll")                                                  \
            for (int nt = 0; nt < 4; ++nt) {                                   \
                const _Float16* vr = (VB) + (l15 + 16 * nt) * 64               \
                    + (((c * 4 + quad) ^ ksw) * 8);                            \
                half8 vf = *(const half8*)vr;                                  \
                acc[0][nt] = mfma_k32(vf, pfrag[0][c], acc[0][nt]);            \
                acc[1][nt] = mfma_k32(vf, pfrag[1][c], acc[1][nt]);            \
            }                                                                  \
        }                                                                      \
        __builtin_amdgcn_s_setprio(0);                                         \
    } while (0)

    STAGE(0, Ksm0, Vsm0);
    for (int kt = 0; kt < NKT; kt += 2) {
        __syncthreads();
        if (kt + 1 < NKT) STAGE(kt + 1, Ksm1, Vsm1);
        COMPUTE(Ksm0, Vsm0);
        __syncthreads();
        if (kt + 2 < NKT) STAGE(kt + 2, Ksm0, Vsm0);
        COMPUTE(Ksm1, Vsm1);
    }

    // ---- epilogue: transpose O^T through LDS, coalesced stores ----
    const int b = bh >> 2, h = bh & 3, ch0 = h * DH;
    floatx4 wp4 = *(const floatx4*)(wp + ch0 + l15 * 4);
    floatx4 bp4 = *(const floatx4*)(bp + ch0 + l15 * 4);
    float inv_l[2];
    #pragma unroll
    for (int g = 0; g < 2; ++g) inv_l[g] = 1.0f / accl[g][0];

    __syncthreads();
    float* Ot = (float*)(pool) + wave * 2304;   // [32 q][72] floats, 9216B/wave
    #pragma unroll
    for (int g = 0; g < 2; ++g) {
        #pragma unroll
        for (int nt = 0; nt < 4; ++nt) {
            floatx4 o;
            #pragma unroll
            for (int r = 0; r < 4; ++r) o[r] = acc[g][nt][r] * inv_l[g];
            *(floatx4*)&Ot[(g * 16 + l15) * 72 + nt * 16 + quad * 4] = o;
        }
    }
    #pragma unroll
    for (int i = 0; i < 8; ++i) {
        int q = i * 4 + quad;
        floatx4 v = *(const floatx4*)&Ot[q * 72 + l15 * 4];
        floatx4 o;
        o.x = v.x * wp4.x + bp4.x;
        o.y = v.y * wp4.y + bp4.y;
        o.z = v.z * wp4.z + bp4.z;
        o.w = v.w * wp4.w + bp4.w;
        *(floatx4*)(out + ((size_t)b * HW + q0 + q) * CCH + ch0 + l15 * 4) = o;
    }
    #undef STAGE
    #undef COMPUTE
}

extern "C" void kernel_launch(void* const* d_in, const int* in_sizes, int n_in,
                              void* d_out, int out_size, void* d_ws, size_t ws_size,
                              hipStream_t stream) {
    const float* q_in = (const float*)d_in[0];
    const float* k_in = (const float*)d_in[1];
    const float* v_in = (const float*)d_in[2];
    const float* wq = (const float*)d_in[3];
    const float* bq = (const float*)d_in[4];
    const float* wk = (const float*)d_in[5];
    const float* bk = (const float*)d_in[6];
    const float* wv = (const float*)d_in[7];
    const float* bv = (const float*)d_in[8];
    const float* wp = (const float*)d_in[9];
    const float* bp = (const float*)d_in[10];
    float* out = (float*)d_out;

    const size_t tensor_halves = (size_t)4 * NH * HW * DH;
    _Float16* Qhat = (_Float16*)d_ws;
    _Float16* Khat = Qhat + tensor_halves;
    _Float16* Vthat = Khat + tensor_halves;

    prepass_all<<<dim3(4096 + 1024), 256, 0, stream>>>(
        q_in, k_in, v_in, wq, bq, wk, bk, wv, bv, Qhat, Khat, Vthat);
    attn_kernel<<<dim3(HW / QTILE, 4 * NH), 256, 0, stream>>>(
        Qhat, Khat, Vthat, wp, bp, out);
}

// Round 5
// 103.987 us; speedup vs baseline: 1.2580x; 1.0192x over previous
//
#include <hip/hip_runtime.h>

// SpatialAttention B=4 HW=4096 C=256 NH=4 d=64 — f16 MFMA flash attention.
// R10 (= R9 + cache locality + counted-vmcnt pipeline):
// Evidence: time invariant to wave count (R6/R7), all pipes <50%, per-tile
// cycle math says ~25-55us achievable -> external floor = shared cache BW.
// Each block reads 1MB K/V; default dispatch spreads same-bh blocks over all
// 8 XCDs -> each 4MB L2 streams the whole 16MB K/V set (thrash -> Infinity
// Cache BW floor). Fix 1: 1-D grid + decode so XCD x gets exactly bh
// {2x,2x+1} (2MB, L2-resident). Fix 2: triple-buffered staging with raw
// s_barrier + s_waitcnt vmcnt(4) (stage t+2 in flight across barrier; no
// more vmcnt(0) drain per tile). WAR-safe: stage-after-barrier writes the
// buffer all waves finished reading one iteration ago.

#define HW 4096
#define CCH 256
#define DH 64
#define NH 4
#define QTILE 128
#define KTILE 64
#define NKT (HW / KTILE)
#define LOG2E 1.44269504088896340736f

typedef __attribute__((ext_vector_type(8))) _Float16 half8;
typedef __attribute__((ext_vector_type(4))) _Float16 half4;
typedef __attribute__((ext_vector_type(2))) __fp16 pk16x2;   // cvt_pkrtz native type
typedef __attribute__((ext_vector_type(4))) float floatx4;

typedef __attribute__((address_space(1))) const unsigned int gbl_u32;
typedef __attribute__((address_space(3))) unsigned int lds_u32;

__device__ __forceinline__ void gload_lds16(const void* g, void* l) {
    __builtin_amdgcn_global_load_lds((gbl_u32*)g, (lds_u32*)l, 16, 0, 0);
}
__device__ __forceinline__ floatx4 mfma_k32(half8 a, half8 b, floatx4 c) {
    return __builtin_amdgcn_mfma_f32_16x16x32_f16(a, b, c, 0, 0, 0);
}
__device__ __forceinline__ float max3f(float a, float b, float c) {
    return fmaxf(fmaxf(a, b), c);   // clang fuses to v_max3_f32
}

// ---------- fused prepass ----------
// blocks [0,4096): Qhat/Khat elementwise (scale*log2e folded into Q).
// Khat rows permuted within each 32-key chunk (see R9 header): makes QK^T
// C/D row map coincide with the k32 PV B-frag k-map, zero cross-lane traffic.
// blocks [4096,5120): Vthat transpose [B*NH][64][HW] (physical key order)
__global__ __launch_bounds__(256) void prepass_all(
    const float* __restrict__ q_in, const float* __restrict__ k_in,
    const float* __restrict__ v_in,
    const float* __restrict__ wq, const float* __restrict__ bq,
    const float* __restrict__ wk, const float* __restrict__ bk,
    const float* __restrict__ wv, const float* __restrict__ bv,
    _Float16* __restrict__ Qhat, _Float16* __restrict__ Khat,
    _Float16* __restrict__ Vthat)
{
    if (blockIdx.x < 4096) {
        int idx = (blockIdx.x * 256 + threadIdx.x) * 4;
        int b = idx >> 20;
        int rem = idx & ((1 << 20) - 1);
        int row = rem >> 8;
        int c = rem & 255;
        int h = c >> 6;
        int ch = c & 63;
        floatx4 q4 = *(const floatx4*)(q_in + idx);
        floatx4 k4 = *(const floatx4*)(k_in + idx);
        floatx4 wq4 = *(const floatx4*)(wq + c);
        floatx4 bq4 = *(const floatx4*)(bq + c);
        floatx4 wk4 = *(const floatx4*)(wk + c);
        floatx4 bk4 = *(const floatx4*)(bk + c);
        const float qsc = 0.125f * LOG2E;
        half4 qh, kh;
        qh[0] = (_Float16)((q4.x * wq4.x + bq4.x) * qsc);
        qh[1] = (_Float16)((q4.y * wq4.y + bq4.y) * qsc);
        qh[2] = (_Float16)((q4.z * wq4.z + bq4.z) * qsc);
        qh[3] = (_Float16)((q4.w * wq4.w + bq4.w) * qsc);
        kh[0] = (_Float16)(k4.x * wk4.x + bk4.x);
        kh[1] = (_Float16)(k4.y * wk4.y + bk4.y);
        kh[2] = (_Float16)(k4.z * wk4.z + bk4.z);
        kh[3] = (_Float16)(k4.w * wk4.w + bk4.w);
        size_t o_q = ((size_t)(b * NH + h) * HW + row) * DH + ch;
        int p = row & 31;
        int srow = ((p & 4) << 2) + ((p >> 3) << 2) + (p & 3);
        int row_k = (row & ~31) | srow;
        size_t o_k = ((size_t)(b * NH + h) * HW + row_k) * DH + ch;
        *(half4*)(Qhat + o_q) = qh;
        *(half4*)(Khat + o_k) = kh;
    } else {
        __shared__ _Float16 Lt[64 * 68];
        int bx = blockIdx.x - 4096;
        int t = threadIdx.x;
        int key0 = (bx & 63) * 64;
        int bh = bx >> 6;
        int b = bh >> 2, h = bh & 3;
        int c4 = (t & 15) * 4;
        floatx4 wv4 = *(const floatx4*)(wv + h * DH + c4);
        floatx4 bv4 = *(const floatx4*)(bv + h * DH + c4);
        #pragma unroll
        for (int p = 0; p < 4; ++p) {
            int key = p * 16 + (t >> 4);
            const float* vp = v_in + ((size_t)b * HW + key0 + key) * CCH + h * DH + c4;
            floatx4 v4 = *(const floatx4*)vp;
            half4 vh;
            vh[0] = (_Float16)(v4.x * wv4.x + bv4.x);
            vh[1] = (_Float16)(v4.y * wv4.y + bv4.y);
            vh[2] = (_Float16)(v4.z * wv4.z + bv4.z);
            vh[3] = (_Float16)(v4.w * wv4.w + bv4.w);
            *(half4*)(&Lt[key * 68 + c4]) = vh;
        }
        __syncthreads();
        #pragma unroll
        for (int p = 0; p < 2; ++p) {
            int ch = p * 32 + (t >> 3);
            int kg = (t & 7) * 8;
            half8 v8;
            #pragma unroll
            for (int j = 0; j < 8; ++j) v8[j] = Lt[(kg + j) * 68 + ch];
            *(half8*)(Vthat + ((size_t)bh * DH + ch) * HW + key0 + kg) = v8;
        }
    }
}

// ---------- attention (transposed, register-P, all-k32, 3-buf pipeline) ----------
__launch_bounds__(256, 3)
__global__ void attn_kernel(
    const _Float16* __restrict__ Qhat, const _Float16* __restrict__ Khat,
    const _Float16* __restrict__ Vthat,
    const float* __restrict__ wp, const float* __restrict__ bp,
    float* __restrict__ out)
{
    // pool: K0|K1|K2 (8KB each) @0, V0|V1|V2 (8KB each) @24576; epilogue Ot @0
    __shared__ alignas(16) char pool[49152];
    _Float16* Ksm0 = (_Float16*)(pool);
    _Float16* Ksm1 = (_Float16*)(pool + 8192);
    _Float16* Ksm2 = (_Float16*)(pool + 16384);
    _Float16* Vsm0 = (_Float16*)(pool + 24576);
    _Float16* Vsm1 = (_Float16*)(pool + 32768);
    _Float16* Vsm2 = (_Float16*)(pool + 40960);

    const int tid = threadIdx.x;
    const int wave = tid >> 6;
    const int lane = tid & 63;
    const int l15 = lane & 15;
    const int quad = lane >> 4;
    const int ksw = l15 & 7;

    // XCD-locality decode: XCD x = f&7 gets bh {2x, 2x+1} (2MB K/V -> L2-fit)
    const int f = blockIdx.x;
    const int xcd = f & 7;
    const int s = f >> 3;
    const int bh = 2 * xcd + (s >> 5);
    const int qtile = s & 31;

    // Q B-frags: B[k=ch][n=q], lane holds ch = quad*8+j (+32), q = l15 (+16g)
    const int q0 = qtile * QTILE + wave * 32;
    half8 qfrag[2][2];
    #pragma unroll
    for (int g = 0; g < 2; ++g) {
        const _Float16* qp = Qhat + ((size_t)bh * HW + q0 + g * 16 + l15) * DH + quad * 8;
        qfrag[g][0] = *(const half8*)(qp);
        qfrag[g][1] = *(const half8*)(qp + 32);
    }

    // staging lane addresses (XOR swizzle of 8-half groups in global addr)
    const int srow0 = lane >> 3;
    const int sw = (lane & 7) ^ srow0;
    const _Float16* kgp0 = Khat + ((size_t)bh * HW + wave * 8 + srow0) * DH + sw * 8;
    const _Float16* kgp1 = kgp0 + (size_t)32 * DH;
    const _Float16* vgp0 = Vthat + ((size_t)bh * DH + wave * 8 + srow0) * HW + sw * 8;
    const _Float16* vgp1 = vgp0 + (size_t)32 * HW;

    half8 ones8;
    #pragma unroll
    for (int j = 0; j < 8; ++j) ones8[j] = (_Float16)1.0f;

    floatx4 acc[2][4];
    floatx4 accl[2];                 // l-sum accumulator (ones-row MFMA); [0] used
    float m_i[2];
    #pragma unroll
    for (int g = 0; g < 2; ++g) {
        m_i[g] = -1e30f;
        floatx4 z = {0.f,0.f,0.f,0.f};
        accl[g] = z;
        #pragma unroll
        for (int nt = 0; nt < 4; ++nt) acc[g][nt] = z;
    }

    #define STAGE(kt, KB, VB) do {                                             \
        gload_lds16(kgp0 + (size_t)(kt) * (KTILE * DH), (KB) + wave * 512);    \
        gload_lds16(kgp1 + (size_t)(kt) * (KTILE * DH), (KB) + 2048 + wave * 512); \
        gload_lds16(vgp0 + (size_t)(kt) * KTILE, (VB) + wave * 512);           \
        gload_lds16(vgp1 + (size_t)(kt) * KTILE, (VB) + 2048 + wave * 512);    \
    } while (0)

    #define COMPUTE(KB, VB) do {                                               \
        floatx4 S[2][4];                                                       \
        __builtin_amdgcn_s_setprio(1);                                         \
        _Pragma("unroll")                                                      \
        for (int kt = 0; kt < 4; ++kt) {                                       \
            const _Float16* kr = (KB) + (l15 + 16 * kt) * 64;                  \
            half8 kf0 = *(const half8*)(kr + ((quad ^ ksw) * 8));              \
            half8 kf1 = *(const half8*)(kr + (((4 + quad) ^ ksw) * 8));        \
            _Pragma("unroll")                                                  \
            for (int g = 0; g < 2; ++g) {                                      \
                floatx4 s2 = {0.f, 0.f, 0.f, 0.f};                             \
                s2 = mfma_k32(kf0, qfrag[g][0], s2);                           \
                s2 = mfma_k32(kf1, qfrag[g][1], s2);                           \
                S[g][kt] = s2;                                                 \
            }                                                                  \
        }                                                                      \
        __builtin_amdgcn_s_setprio(0);                                         \
        float mxa[2];                                                          \
        _Pragma("unroll")                                                      \
        for (int g = 0; g < 2; ++g) {                                          \
            float t0 = max3f(S[g][0][0], S[g][0][1], S[g][0][2]);              \
            float t1 = max3f(S[g][0][3], S[g][1][0], S[g][1][1]);              \
            float t2 = max3f(S[g][1][2], S[g][1][3], S[g][2][0]);              \
            float t3 = max3f(S[g][2][1], S[g][2][2], S[g][2][3]);              \
            float t4 = max3f(S[g][3][0], S[g][3][1], S[g][3][2]);              \
            float u0 = max3f(t0, t1, S[g][3][3]);                              \
            float u1 = fmaxf(t2, fmaxf(t3, t4));                               \
            float mx = fmaxf(u0, u1);                                          \
            mx = fmaxf(mx, __shfl_xor(mx, 16));                                \
            mx = fmaxf(mx, __shfl_xor(mx, 32));                                \
            mxa[g] = mx;                                                       \
        }                                                                      \
        bool ok = (mxa[0] <= m_i[0] + 8.0f) && (mxa[1] <= m_i[1] + 8.0f);      \
        if (!__all(ok)) {                                                      \
            _Pragma("unroll")                                                  \
            for (int g = 0; g < 2; ++g) {                                      \
                float nm = fmaxf(m_i[g], mxa[g]);                              \
                float alpha = __builtin_amdgcn_exp2f(m_i[g] - nm);             \
                accl[g][0] *= alpha;                                           \
                _Pragma("unroll")                                              \
                for (int nt = 0; nt < 4; ++nt) acc[g][nt] *= alpha;            \
                m_i[g] = nm;                                                   \
            }                                                                  \
        }                                                                      \
        half8 pfrag[2][2];                                                     \
        _Pragma("unroll")                                                      \
        for (int g = 0; g < 2; ++g) {                                          \
            float nm = m_i[g];                                                 \
            _Pragma("unroll")                                                  \
            for (int c = 0; c < 2; ++c) {                                      \
                float a0 = __builtin_amdgcn_exp2f(S[g][2*c][0] - nm);          \
                float a1 = __builtin_amdgcn_exp2f(S[g][2*c][1] - nm);          \
                float a2 = __builtin_amdgcn_exp2f(S[g][2*c][2] - nm);          \
                float a3 = __builtin_amdgcn_exp2f(S[g][2*c][3] - nm);          \
                float b0 = __builtin_amdgcn_exp2f(S[g][2*c+1][0] - nm);        \
                float b1 = __builtin_amdgcn_exp2f(S[g][2*c+1][1] - nm);        \
                float b2 = __builtin_amdgcn_exp2f(S[g][2*c+1][2] - nm);        \
                float b3 = __builtin_amdgcn_exp2f(S[g][2*c+1][3] - nm);        \
                pk16x2 p01 = __builtin_amdgcn_cvt_pkrtz(a0, a1);               \
                pk16x2 p23 = __builtin_amdgcn_cvt_pkrtz(a2, a3);               \
                pk16x2 p45 = __builtin_amdgcn_cvt_pkrtz(b0, b1);               \
                pk16x2 p67 = __builtin_amdgcn_cvt_pkrtz(b2, b3);               \
                half8 pk;                                                      \
                pk[0] = (_Float16)p01[0]; pk[1] = (_Float16)p01[1];            \
                pk[2] = (_Float16)p23[0]; pk[3] = (_Float16)p23[1];            \
                pk[4] = (_Float16)p45[0]; pk[5] = (_Float16)p45[1];            \
                pk[6] = (_Float16)p67[0]; pk[7] = (_Float16)p67[1];            \
                pfrag[g][c] = pk;                                              \
            }                                                                  \
        }                                                                      \
        __builtin_amdgcn_s_setprio(1);                                         \
        _Pragma("unroll")                                                      \
        for (int c = 0; c < 2; ++c) {                                          \
            accl[0] = mfma_k32(ones8, pfrag[0][c], accl[0]);                   \
            accl[1] = mfma_k32(ones8, pfrag[1][c], accl[1]);                   \
            _Pragma("unroll")                                                  \
            for (int nt = 0; nt < 4; ++nt) {                                   \
                const _Float16* vr = (VB) + (l15 + 16 * nt) * 64               \
                    + (((c * 4 + quad) ^ ksw) * 8);                            \
                half8 vf = *(const half8*)vr;                                  \
                acc[0][nt] = mfma_k32(vf, pfrag[0][c], acc[0][nt]);            \
                acc[1][nt] = mfma_k32(vf, pfrag[1][c], acc[1][nt]);            \
            }                                                                  \
        }                                                                      \
        __builtin_amdgcn_s_setprio(0);                                         \
    } while (0)

    // counted-vmcnt pipeline: vmcnt(4) -> STAGE(t) landed (STAGE(t+1) in
    // flight); barrier -> all waves' STAGE(t) landed AND all finished
    // COMPUTE(t-1); then STAGE(t+2) safely overwrites buf[(t-1)%3].
    #define WAITVM(n) asm volatile("s_waitcnt vmcnt(" #n ")" ::: "memory")
    #define ITER_FULL(t2, KB, VB, KBn, VBn) do {                               \
        WAITVM(4);                                                             \
        __builtin_amdgcn_s_barrier();                                          \
        __builtin_amdgcn_sched_barrier(0);                                     \
        STAGE(t2, KBn, VBn);                                                   \
        COMPUTE(KB, VB);                                                       \
    } while (0)
    #define ITER_TAIL(vm, KB, VB) do {                                         \
        WAITVM(vm);                                                            \
        __builtin_amdgcn_s_barrier();                                          \
        __builtin_amdgcn_sched_barrier(0);                                     \
        COMPUTE(KB, VB);                                                       \
    } while (0)

    STAGE(0, Ksm0, Vsm0);
    STAGE(1, Ksm1, Vsm1);
    for (int t = 0; t < 60; t += 3) {
        ITER_FULL(t + 2, Ksm0, Vsm0, Ksm2, Vsm2);
        ITER_FULL(t + 3, Ksm1, Vsm1, Ksm0, Vsm0);
        ITER_FULL(t + 4, Ksm2, Vsm2, Ksm1, Vsm1);
    }
    ITER_FULL(62, Ksm0, Vsm0, Ksm2, Vsm2);   // compute t=60
    ITER_FULL(63, Ksm1, Vsm1, Ksm0, Vsm0);   // compute t=61
    ITER_TAIL(4, Ksm2, Vsm2);                // compute t=62 (63 in flight)
    ITER_TAIL(0, Ksm0, Vsm0);                // compute t=63

    // ---- epilogue: transpose O^T through LDS, coalesced stores ----
    const int b = bh >> 2, h = bh & 3, ch0 = h * DH;
    floatx4 wp4 = *(const floatx4*)(wp + ch0 + l15 * 4);
    floatx4 bp4 = *(const floatx4*)(bp + ch0 + l15 * 4);
    float inv_l[2];
    #pragma unroll
    for (int g = 0; g < 2; ++g) inv_l[g] = 1.0f / accl[g][0];

    __syncthreads();
    float* Ot = (float*)(pool) + wave * 2304;   // [32 q][72] floats, 9216B/wave
    #pragma unroll
    for (int g = 0; g < 2; ++g) {
        #pragma unroll
        for (int nt = 0; nt < 4; ++nt) {
            floatx4 o;
            #pragma unroll
            for (int r = 0; r < 4; ++r) o[r] = acc[g][nt][r] * inv_l[g];
            *(floatx4*)&Ot[(g * 16 + l15) * 72 + nt * 16 + quad * 4] = o;
        }
    }
    #pragma unroll
    for (int i = 0; i < 8; ++i) {
        int q = i * 4 + quad;
        floatx4 v = *(const floatx4*)&Ot[q * 72 + l15 * 4];
        floatx4 o;
        o.x = v.x * wp4.x + bp4.x;
        o.y = v.y * wp4.y + bp4.y;
        o.z = v.z * wp4.z + bp4.z;
        o.w = v.w * wp4.w + bp4.w;
        *(floatx4*)(out + ((size_t)b * HW + q0 + q) * CCH + ch0 + l15 * 4) = o;
    }
    #undef STAGE
    #undef COMPUTE
    #undef WAITVM
    #undef ITER_FULL
    #undef ITER_TAIL
}

extern "C" void kernel_launch(void* const* d_in, const int* in_sizes, int n_in,
                              void* d_out, int out_size, void* d_ws, size_t ws_size,
                              hipStream_t stream) {
    const float* q_in = (const float*)d_in[0];
    const float* k_in = (const float*)d_in[1];
    const float* v_in = (const float*)d_in[2];
    const float* wq = (const float*)d_in[3];
    const float* bq = (const float*)d_in[4];
    const float* wk = (const float*)d_in[5];
    const float* bk = (const float*)d_in[6];
    const float* wv = (const float*)d_in[7];
    const float* bv = (const float*)d_in[8];
    const float* wp = (const float*)d_in[9];
    const float* bp = (const float*)d_in[10];
    float* out = (float*)d_out;

    const size_t tensor_halves = (size_t)4 * NH * HW * DH;
    _Float16* Qhat = (_Float16*)d_ws;
    _Float16* Khat = Qhat + tensor_halves;
    _Float16* Vthat = Khat + tensor_halves;

    prepass_all<<<dim3(4096 + 1024), 256, 0, stream>>>(
        q_in, k_in, v_in, wq, bq, wk, bk, wv, bv, Qhat, Khat, Vthat);
    attn_kernel<<<dim3(HW / QTILE * 4 * NH), 256, 0, stream>>>(
        Qhat, Khat, Vthat, wp, bp, out);
}